// Round 1
// baseline (7129.801 us; speedup 1.0000x reference)
//
#include <hip/hip_runtime.h>
#include <math.h>

#define BB 4
#define NN 2048
#define DD 512
#define HEADS_E 4
#define LAMBDA_INIT 0.8f
#define EPSV 1e-5f

// One block (256 threads) per (b, he, q_row).
// LDS holds both heads' score rows (2 x 2048 fp32), full softmax, diff, PV, RMSNorm.
__global__ __launch_bounds__(256) void attn_kernel(
    const float* __restrict__ q, const float* __restrict__ k, const float* __restrict__ v,
    const float* __restrict__ lq1, const float* __restrict__ lk1,
    const float* __restrict__ lq2, const float* __restrict__ lk2,
    const float* __restrict__ norm_w, float* __restrict__ X)
{
    __shared__ float s1[NN];
    __shared__ float s2[NN];
    __shared__ __align__(16) float qs[128];
    __shared__ float red[256];
    __shared__ float lam_sh;

    const int t = threadIdx.x;
    int bid = blockIdx.x;
    const int n  = bid & (NN - 1); bid >>= 11;
    const int he = bid & 3;
    const int b  = bid >> 2;

    // lambda scalar (cheap, per block)
    if (t < 64) {
        float p1 = lq1[t] * lk1[t];
        float p2 = lq2[t] * lk2[t];
        #pragma unroll
        for (int off = 32; off; off >>= 1) {
            p1 += __shfl_xor(p1, off);
            p2 += __shfl_xor(p2, off);
        }
        if (t == 0) lam_sh = __expf(p1) - __expf(p2) + LAMBDA_INIT;
    }
    // q1 (cols he*128..+64) and q2 (next 64) are contiguous 128 floats
    if (t < 128) qs[t] = q[((size_t)(b * NN + n)) * DD + he * 128 + t] * 0.125f;
    __syncthreads();
    const float lam = lam_sh;

    // ---- scores for both heads ----
    {
        const float* kb = k + (size_t)b * NN * DD + he * 128;
        const float4* q4 = (const float4*)qs;
        for (int kk = t; kk < NN; kk += 256) {
            const float4* kr = (const float4*)(kb + (size_t)kk * DD);
            float a1 = 0.f, a2 = 0.f;
            #pragma unroll
            for (int i = 0; i < 16; ++i) {
                float4 kv = kr[i];
                float4 qv = q4[i];
                a1 += kv.x * qv.x + kv.y * qv.y + kv.z * qv.z + kv.w * qv.w;
            }
            #pragma unroll
            for (int i = 16; i < 32; ++i) {
                float4 kv = kr[i];
                float4 qv = q4[i];
                a2 += kv.x * qv.x + kv.y * qv.y + kv.z * qv.z + kv.w * qv.w;
            }
            s1[kk] = a1;
            s2[kk] = a2;
        }
    }
    __syncthreads();

    // ---- softmax over each score row ----
    float invs[2];
    {
        float* sp0 = s1;
        float* sp1 = s2;
        #pragma unroll
        for (int h = 0; h < 2; ++h) {
            float* s = (h == 0) ? sp0 : sp1;
            float m = -INFINITY;
            for (int kk = t; kk < NN; kk += 256) m = fmaxf(m, s[kk]);
            red[t] = m; __syncthreads();
            for (int st = 128; st; st >>= 1) {
                if (t < st) red[t] = fmaxf(red[t], red[t + st]);
                __syncthreads();
            }
            m = red[0]; __syncthreads();
            float sum = 0.f;
            for (int kk = t; kk < NN; kk += 256) {
                float e = __expf(s[kk] - m);
                s[kk] = e;
                sum += e;
            }
            red[t] = sum; __syncthreads();
            for (int st = 128; st; st >>= 1) {
                if (t < st) red[t] += red[t + st];
                __syncthreads();
            }
            invs[h] = 1.f / red[0];
            __syncthreads();
        }
    }

    // ---- diff = p1 - lam*p2 (into s1) ----
    for (int kk = t; kk < NN; kk += 256)
        s1[kk] = s1[kk] * invs[0] - lam * (s2[kk] * invs[1]);
    __syncthreads();

    // ---- PV: out[d] = sum_k diff[k] * v[k][d], d in [0,128) ----
    {
        const int d    = t & 127;
        const int half = t >> 7;
        const float* vb = v + (size_t)b * NN * DD + he * 128 + d;
        float acc = 0.f;
        const int k0 = half * (NN / 2);
        #pragma unroll 8
        for (int kk = k0; kk < k0 + NN / 2; ++kk)
            acc = fmaf(s1[kk], vb[(size_t)kk * DD], acc);
        red[t] = acc;
        __syncthreads();
        float o = 0.f;
        if (t < 128) o = red[t] + red[t + 128];
        __syncthreads();
        red[t] = (t < 128) ? o * o : 0.f;
        __syncthreads();
        for (int st = 128; st; st >>= 1) {
            if (t < st) red[t] += red[t + st];
            __syncthreads();
        }
        if (t < 128) {
            float ms = red[0] * (1.f / 128.f);
            float val = o * rsqrtf(ms + EPSV) * norm_w[t] * 0.2f; // (1-LAMBDA_INIT)=0.2
            X[((size_t)(b * NN + n)) * DD + he * 128 + t] = val;
        }
    }
}

// ---- projection: out[i][j] = sum_k X[i][k]*W[j][k] + bias[j] ----
#define BM 64
#define BN 64
#define BK 16
__global__ __launch_bounds__(256) void proj_kernel(
    const float* __restrict__ X, const float* __restrict__ W,
    const float* __restrict__ bias, float* __restrict__ out)
{
    __shared__ float As[BM][BK + 1];
    __shared__ float Bs[BN][BK + 1];
    const int tid  = threadIdx.x;
    const int row0 = blockIdx.x * BM;
    const int col0 = blockIdx.y * BN;
    const int lr = tid >> 2;          // 0..63
    const int lc = (tid & 3) << 2;    // 0,4,8,12
    const int ty = tid >> 4;          // 0..15 -> rows
    const int tx = tid & 15;          // 0..15 -> cols
    float acc[4][4] = {};

    for (int k0 = 0; k0 < DD; k0 += BK) {
        float4 av = *(const float4*)&X[(size_t)(row0 + lr) * DD + k0 + lc];
        float4 bv = *(const float4*)&W[(size_t)(col0 + lr) * DD + k0 + lc];
        As[lr][lc] = av.x; As[lr][lc + 1] = av.y; As[lr][lc + 2] = av.z; As[lr][lc + 3] = av.w;
        Bs[lr][lc] = bv.x; Bs[lr][lc + 1] = bv.y; Bs[lr][lc + 2] = bv.z; Bs[lr][lc + 3] = bv.w;
        __syncthreads();
        #pragma unroll
        for (int kk = 0; kk < BK; ++kk) {
            float a[4], bb[4];
            #pragma unroll
            for (int i = 0; i < 4; ++i) a[i] = As[ty * 4 + i][kk];
            #pragma unroll
            for (int j = 0; j < 4; ++j) bb[j] = Bs[tx * 4 + j][kk];
            #pragma unroll
            for (int i = 0; i < 4; ++i)
                #pragma unroll
                for (int j = 0; j < 4; ++j)
                    acc[i][j] = fmaf(a[i], bb[j], acc[i][j]);
        }
        __syncthreads();
    }
    #pragma unroll
    for (int i = 0; i < 4; ++i) {
        const int r = row0 + ty * 4 + i;
        #pragma unroll
        for (int j = 0; j < 4; ++j) {
            const int c = col0 + tx * 4 + j;
            out[(size_t)r * DD + c] = acc[i][j] + bias[c];
        }
    }
}

extern "C" void kernel_launch(void* const* d_in, const int* in_sizes, int n_in,
                              void* d_out, int out_size, void* d_ws, size_t ws_size,
                              hipStream_t stream) {
    const float* q      = (const float*)d_in[0];
    const float* k      = (const float*)d_in[1];
    const float* v      = (const float*)d_in[2];
    const float* lq1    = (const float*)d_in[3];
    const float* lk1    = (const float*)d_in[4];
    const float* lq2    = (const float*)d_in[5];
    const float* lk2    = (const float*)d_in[6];
    const float* norm_w = (const float*)d_in[7];
    const float* out_w  = (const float*)d_in[8];
    const float* out_b  = (const float*)d_in[9];
    float* out = (float*)d_out;
    float* X   = (float*)d_ws;   // [B,N,512] fp32 = 16.8 MB

    attn_kernel<<<BB * HEADS_E * NN, 256, 0, stream>>>(
        q, k, v, lq1, lk1, lq2, lk2, norm_w, X);

    dim3 grid((BB * NN) / BM, DD / BN);
    proj_kernel<<<grid, 256, 0, stream>>>(X, out_w, out_b, out);
}

// Round 2
// 237.568 us; speedup vs baseline: 30.0116x; 30.0116x over previous
//
#include <hip/hip_runtime.h>
#include <math.h>

#define BB 4
#define NN 2048
#define DD 512
#define HE_N 4
#define LAMBDA_INIT 0.8f
#define EPSV 1e-5f
#define BM 64
#define BKV 64

typedef __attribute__((ext_vector_type(8))) short bf16x8;
typedef __attribute__((ext_vector_type(4))) float f32x4;
typedef unsigned short u16;
typedef __attribute__((ext_vector_type(4))) u16 u16x4;
typedef __attribute__((ext_vector_type(8))) u16 u16x8;

__device__ __forceinline__ u16 f2bf(float f) {
  unsigned u = __builtin_bit_cast(unsigned, f);
  u = (u + 0x7FFFu + ((u >> 16) & 1u)) >> 16;
  return (u16)u;
}

__device__ __forceinline__ bf16x8 pack8(const float4& a, const float4& bq) {
  bf16x8 r;
  r[0]=(short)f2bf(a.x);  r[1]=(short)f2bf(a.y);  r[2]=(short)f2bf(a.z);  r[3]=(short)f2bf(a.w);
  r[4]=(short)f2bf(bq.x); r[5]=(short)f2bf(bq.y); r[6]=(short)f2bf(bq.z); r[7]=(short)f2bf(bq.w);
  return r;
}

// ---- prepass: Vbt[b][he][d(128)][n(2048)] bf16 = v[b][n][he*128+d] ----
__global__ __launch_bounds__(256) void vt_kernel(const float* __restrict__ v, u16* __restrict__ Vbt) {
  __shared__ u16 Ls[64][73];
  const int t = threadIdx.x;
  const int n0 = blockIdx.x * 64;
  const int d0 = blockIdx.y * 64;
  const int z  = blockIdx.z;           // b*4+he
  #pragma unroll
  for (int p = 0; p < 4; ++p) {
    int n = p*16 + (t>>4), f4 = t & 15;
    float4 rv = *(const float4*)&v[((size_t)((z>>2)*NN + n0 + n))*DD + (z&3)*128 + d0 + f4*4];
    Ls[n][f4*4+0] = f2bf(rv.x); Ls[n][f4*4+1] = f2bf(rv.y);
    Ls[n][f4*4+2] = f2bf(rv.z); Ls[n][f4*4+3] = f2bf(rv.w);
  }
  __syncthreads();
  #pragma unroll
  for (int p = 0; p < 4; ++p) {
    int d = p*16 + (t>>4), c4 = t & 15;
    u16x4 o;
    #pragma unroll
    for (int j = 0; j < 4; ++j) o[j] = Ls[c4*4+j][d];
    *(u16x4*)&Vbt[((size_t)z*128 + d0 + d)*NN + n0 + c4*4] = o;
  }
}

// ---- fused diff-attention, MFMA bf16, online softmax x2, RMSNorm epilogue ----
__global__ __launch_bounds__(256, 2) void attn_mfma_kernel(
    const float* __restrict__ q, const float* __restrict__ k,
    const u16* __restrict__ Vbt,
    const float* __restrict__ lq1, const float* __restrict__ lk1,
    const float* __restrict__ lq2, const float* __restrict__ lk2,
    const float* __restrict__ norm_w, float* __restrict__ X)
{
  __shared__ __align__(16) u16 Ks[64*128];    // K tile, 256B rows, XOR-swizzled
  __shared__ __align__(16) u16 Vts[128*64];   // V^T tile, 128B rows, XOR-swizzled
  __shared__ __align__(16) u16 Pl[4][2][16][72];
  __shared__ float lam_sh;

  const int t = threadIdx.x;
  const int w = t >> 6;
  const int l = t & 63;
  const int g = l >> 4;
  const int c = l & 15;

  int bid = blockIdx.x;
  const int qt = bid & 31; const int he = (bid>>5)&3; const int b = bid>>7;
  const int q0 = qt * BM;
  const int bhe = b*4 + he;

  if (t < 64) {
    float p1 = lq1[t]*lk1[t], p2 = lq2[t]*lk2[t];
    #pragma unroll
    for (int off=32; off; off>>=1) { p1 += __shfl_xor(p1,off); p2 += __shfl_xor(p2,off); }
    if (t==0) lam_sh = __expf(p1) - __expf(p2) + LAMBDA_INIT;
  }

  // Q fragments (A-layout): row=c, k = dk*32 + g*8 + j ; scale 1/8 folded in
  bf16x8 qf[4];
  {
    const float* qp = q + ((size_t)(b*NN) + q0 + w*16 + c)*DD + he*128 + g*8;
    #pragma unroll
    for (int dk=0; dk<4; ++dk) {
      float4 a = *(const float4*)(qp + dk*32);
      float4 bq = *(const float4*)(qp + dk*32 + 4);
      a.x*=0.125f; a.y*=0.125f; a.z*=0.125f; a.w*=0.125f;
      bq.x*=0.125f; bq.y*=0.125f; bq.z*=0.125f; bq.w*=0.125f;
      qf[dk] = pack8(a, bq);
    }
  }

  f32x4 O1[8], O2[8];
  #pragma unroll
  for (int dt=0; dt<8; ++dt) { O1[dt]=(f32x4){0,0,0,0}; O2[dt]=(f32x4){0,0,0,0}; }
  float m1[4], l1[4], m2[4], l2[4];
  #pragma unroll
  for (int r=0;r<4;++r){ m1[r]=-INFINITY; m2[r]=-INFINITY; l1[r]=0.f; l2[r]=0.f; }

  float nw[8];
  #pragma unroll
  for (int dt=0; dt<8; ++dt) nw[dt] = norm_w[dt*16 + c];

  const size_t kbase = ((size_t)(b*NN))*DD + he*128;

  for (int kv0 = 0; kv0 < NN; kv0 += BKV) {
    // issue global loads (regs) before barrier
    float4 ka[4], kb2[4]; u16x8 va[4];
    #pragma unroll
    for (int p = 0; p < 4; ++p) {
      int idx = p*256 + t;
      int r = idx >> 4, cc = idx & 15;
      const float* kp = k + kbase + (size_t)(kv0 + r)*DD + cc*8;
      ka[p]  = *(const float4*)kp;
      kb2[p] = *(const float4*)(kp + 4);
    }
    #pragma unroll
    for (int p = 0; p < 4; ++p) {
      int idx = p*256 + t;
      int d = idx >> 3, cc = idx & 7;
      va[p] = *(const u16x8*)&Vbt[((size_t)bhe*128 + d)*NN + kv0 + cc*8];
    }
    __syncthreads();   // previous tile's reads complete
    #pragma unroll
    for (int p = 0; p < 4; ++p) {
      int idx = p*256 + t;
      int r = idx >> 4, cc = idx & 15;
      *(bf16x8*)&Ks[r*128 + ((cc*8) ^ ((r&7)<<3))] = pack8(ka[p], kb2[p]);
    }
    #pragma unroll
    for (int p = 0; p < 4; ++p) {
      int idx = p*256 + t;
      int d = idx >> 3, cc = idx & 7;
      *(u16x8*)&Vts[d*64 + ((cc*8) ^ ((d&7)<<3))] = va[p];
    }
    __syncthreads();   // tile staged

    // ---- scores: S1 (head1, d 0..63), S2 (head2, d 64..127) ----
    f32x4 s1a[4], s2a[4];
    #pragma unroll
    for (int kvt = 0; kvt < 4; ++kvt) {
      const int row = kvt*16 + c;
      const int sw = (c & 7) << 3;
      const u16* kr = &Ks[row*128];
      bf16x8 k0 = *(const bf16x8*)&kr[(g*8)      ^ sw];
      bf16x8 k1 = *(const bf16x8*)&kr[(32+g*8)   ^ sw];
      bf16x8 k2 = *(const bf16x8*)&kr[(64+g*8)   ^ sw];
      bf16x8 k3 = *(const bf16x8*)&kr[(96+g*8)   ^ sw];
      f32x4 a1 = {0,0,0,0}, a2 = {0,0,0,0};
      a1 = __builtin_amdgcn_mfma_f32_16x16x32_bf16(qf[0], k0, a1, 0,0,0);
      a1 = __builtin_amdgcn_mfma_f32_16x16x32_bf16(qf[1], k1, a1, 0,0,0);
      a2 = __builtin_amdgcn_mfma_f32_16x16x32_bf16(qf[2], k2, a2, 0,0,0);
      a2 = __builtin_amdgcn_mfma_f32_16x16x32_bf16(qf[3], k3, a2, 0,0,0);
      s1a[kvt] = a1; s2a[kvt] = a2;
    }

    // ---- online softmax, both heads; rows owned per (g, r) ----
    #pragma unroll
    for (int r = 0; r < 4; ++r) {
      {
        float mt = fmaxf(fmaxf(s1a[0][r], s1a[1][r]), fmaxf(s1a[2][r], s1a[3][r]));
        mt = fmaxf(mt, __shfl_xor(mt,1)); mt = fmaxf(mt, __shfl_xor(mt,2));
        mt = fmaxf(mt, __shfl_xor(mt,4)); mt = fmaxf(mt, __shfl_xor(mt,8));
        float mn = fmaxf(m1[r], mt);
        float sc = __expf(m1[r] - mn);
        m1[r] = mn;
        float rs = 0.f;
        #pragma unroll
        for (int kvt = 0; kvt < 4; ++kvt) { float p = __expf(s1a[kvt][r]-mn); s1a[kvt][r]=p; rs+=p; }
        rs += __shfl_xor(rs,1); rs += __shfl_xor(rs,2); rs += __shfl_xor(rs,4); rs += __shfl_xor(rs,8);
        l1[r] = l1[r]*sc + rs;
        #pragma unroll
        for (int dt = 0; dt < 8; ++dt) O1[dt][r] *= sc;
      }
      {
        float mt = fmaxf(fmaxf(s2a[0][r], s2a[1][r]), fmaxf(s2a[2][r], s2a[3][r]));
        mt = fmaxf(mt, __shfl_xor(mt,1)); mt = fmaxf(mt, __shfl_xor(mt,2));
        mt = fmaxf(mt, __shfl_xor(mt,4)); mt = fmaxf(mt, __shfl_xor(mt,8));
        float mn = fmaxf(m2[r], mt);
        float sc = __expf(m2[r] - mn);
        m2[r] = mn;
        float rs = 0.f;
        #pragma unroll
        for (int kvt = 0; kvt < 4; ++kvt) { float p = __expf(s2a[kvt][r]-mn); s2a[kvt][r]=p; rs+=p; }
        rs += __shfl_xor(rs,1); rs += __shfl_xor(rs,2); rs += __shfl_xor(rs,4); rs += __shfl_xor(rs,8);
        l2[r] = l2[r]*sc + rs;
        #pragma unroll
        for (int dt = 0; dt < 8; ++dt) O2[dt][r] *= sc;
      }
    }

    // ---- P -> LDS (C-layout scatter), read back in A-layout ----
    #pragma unroll
    for (int kvt = 0; kvt < 4; ++kvt)
      #pragma unroll
      for (int r = 0; r < 4; ++r) {
        Pl[w][0][g*4+r][kvt*16+c] = f2bf(s1a[kvt][r]);
        Pl[w][1][g*4+r][kvt*16+c] = f2bf(s2a[kvt][r]);
      }

    // ---- PV ----
    #pragma unroll
    for (int kvk = 0; kvk < 2; ++kvk) {
      bf16x8 p1 = *(const bf16x8*)&Pl[w][0][c][kvk*32 + g*8];
      bf16x8 p2 = *(const bf16x8*)&Pl[w][1][c][kvk*32 + g*8];
      #pragma unroll
      for (int dt = 0; dt < 8; ++dt) {
        bf16x8 vf = *(const bf16x8*)&Vts[(dt*16+c)*64 + ((kvk*32 + g*8) ^ ((c&7)<<3))];
        O1[dt] = __builtin_amdgcn_mfma_f32_16x16x32_bf16(p1, vf, O1[dt], 0,0,0);
        O2[dt] = __builtin_amdgcn_mfma_f32_16x16x32_bf16(p2, vf, O2[dt], 0,0,0);
      }
    }
  }

  // ---- epilogue: diff, RMSNorm, store X ----
  const float lam = lam_sh;
  float rstd[4];
  #pragma unroll
  for (int r = 0; r < 4; ++r) {
    float i1 = 1.f / l1[r], i2 = lam / l2[r];
    float s = 0.f;
    #pragma unroll
    for (int dt = 0; dt < 8; ++dt) {
      float o = O1[dt][r]*i1 - O2[dt][r]*i2;
      O1[dt][r] = o;
      s += o*o;
    }
    s += __shfl_xor(s,1); s += __shfl_xor(s,2); s += __shfl_xor(s,4); s += __shfl_xor(s,8);
    rstd[r] = rsqrtf(s*(1.f/128.f) + EPSV);
  }
  #pragma unroll
  for (int dt = 0; dt < 8; ++dt)
    #pragma unroll
    for (int r = 0; r < 4; ++r) {
      int qrow = q0 + w*16 + g*4 + r;
      X[((size_t)(b*NN + qrow))*DD + he*128 + dt*16 + c] = O1[dt][r]*rstd[r]*nw[dt]*0.2f;
    }
}

// ---- projection: out[i][j] = sum_k X[i][k]*W[j][k] + bias[j] ----
#define PBM 64
#define PBN 64
#define PBK 16
__global__ __launch_bounds__(256) void proj_kernel(
    const float* __restrict__ X, const float* __restrict__ W,
    const float* __restrict__ bias, float* __restrict__ out)
{
    __shared__ float As[PBM][PBK + 1];
    __shared__ float Bs[PBN][PBK + 1];
    const int tid  = threadIdx.x;
    const int row0 = blockIdx.x * PBM;
    const int col0 = blockIdx.y * PBN;
    const int lr = tid >> 2;
    const int lc = (tid & 3) << 2;
    const int ty = tid >> 4;
    const int tx = tid & 15;
    float acc[4][4] = {};

    for (int k0 = 0; k0 < DD; k0 += PBK) {
        float4 av = *(const float4*)&X[(size_t)(row0 + lr) * DD + k0 + lc];
        float4 bv = *(const float4*)&W[(size_t)(col0 + lr) * DD + k0 + lc];
        As[lr][lc] = av.x; As[lr][lc + 1] = av.y; As[lr][lc + 2] = av.z; As[lr][lc + 3] = av.w;
        Bs[lr][lc] = bv.x; Bs[lr][lc + 1] = bv.y; Bs[lr][lc + 2] = bv.z; Bs[lr][lc + 3] = bv.w;
        __syncthreads();
        #pragma unroll
        for (int kk = 0; kk < PBK; ++kk) {
            float a[4], bb[4];
            #pragma unroll
            for (int i = 0; i < 4; ++i) a[i] = As[ty * 4 + i][kk];
            #pragma unroll
            for (int j = 0; j < 4; ++j) bb[j] = Bs[tx * 4 + j][kk];
            #pragma unroll
            for (int i = 0; i < 4; ++i)
                #pragma unroll
                for (int j = 0; j < 4; ++j)
                    acc[i][j] = fmaf(a[i], bb[j], acc[i][j]);
        }
        __syncthreads();
    }
    #pragma unroll
    for (int i = 0; i < 4; ++i) {
        const int r = row0 + ty * 4 + i;
        #pragma unroll
        for (int j = 0; j < 4; ++j) {
            const int cc = col0 + tx * 4 + j;
            out[(size_t)r * DD + cc] = acc[i][j] + bias[cc];
        }
    }
}

extern "C" void kernel_launch(void* const* d_in, const int* in_sizes, int n_in,
                              void* d_out, int out_size, void* d_ws, size_t ws_size,
                              hipStream_t stream) {
    const float* q      = (const float*)d_in[0];
    const float* k      = (const float*)d_in[1];
    const float* v      = (const float*)d_in[2];
    const float* lq1    = (const float*)d_in[3];
    const float* lk1    = (const float*)d_in[4];
    const float* lq2    = (const float*)d_in[5];
    const float* lk2    = (const float*)d_in[6];
    const float* norm_w = (const float*)d_in[7];
    const float* out_w  = (const float*)d_in[8];
    const float* out_b  = (const float*)d_in[9];
    float* out = (float*)d_out;

    u16*   Vbt = (u16*)d_ws;                              // 8,388,608 B
    float* X   = (float*)((char*)d_ws + 8388608);         // 16,777,216 B

    vt_kernel<<<dim3(32, 2, 16), 256, 0, stream>>>(v, Vbt);
    attn_mfma_kernel<<<512, 256, 0, stream>>>(q, k, Vbt, lq1, lk1, lq2, lk2, norm_w, X);
    proj_kernel<<<dim3((BB*NN)/PBM, DD/PBN), 256, 0, stream>>>(X, out_w, out_b, out);
}

// Round 3
// 136.095 us; speedup vs baseline: 52.3884x; 1.7456x over previous
//
#include <hip/hip_runtime.h>
#include <math.h>

#define BB 4
#define NN 2048
#define DD 512
#define LAMBDA_INIT 0.8f
#define EPSV 1e-5f

typedef __attribute__((ext_vector_type(8))) short bf16x8;
typedef __attribute__((ext_vector_type(4))) float f32x4;
typedef unsigned short u16;
typedef __attribute__((ext_vector_type(4))) u16 u16x4;
typedef __attribute__((ext_vector_type(8))) u16 u16x8;
typedef __attribute__((ext_vector_type(4))) unsigned u32x4;

__device__ __forceinline__ u16 f2bf(float f) {
  unsigned u = __builtin_bit_cast(unsigned, f);
  u = (u + 0x7FFFu + ((u >> 16) & 1u)) >> 16;
  return (u16)u;
}

__device__ __forceinline__ void gload16(const void* g, void* l) {
  __builtin_amdgcn_global_load_lds((const __attribute__((address_space(1))) unsigned*)g,
                                   (__attribute__((address_space(3))) unsigned*)l, 16, 0, 0);
}

// ---- prepass: Q bf16 (scaled by 0.125*log2e, linear), K bf16 pre-swizzled per (b,he) ----
__global__ __launch_bounds__(256) void qk_prep_kernel(
    const float* __restrict__ q, const float* __restrict__ k,
    u16* __restrict__ Qb, u16* __restrict__ Kb)
{
  const int t = threadIdx.x;
  const size_t row = blockIdx.x;          // b*NN + n
  const int n = blockIdx.x & (NN - 1);
  const int b = blockIdx.x >> 11;
  if (t < 128) {
    const float s = 0.125f * 1.4426950408889634f;
    float4 f = *(const float4*)&q[row * DD + t * 4];
    u16x4 o = { f2bf(f.x * s), f2bf(f.y * s), f2bf(f.z * s), f2bf(f.w * s) };
    *(u16x4*)&Qb[row * DD + t * 4] = o;
  } else {
    const int f0 = (t - 128) * 4;
    float4 f = *(const float4*)&k[row * DD + f0];
    const int he = f0 >> 7, fi = f0 & 127;
    const int gi = fi >> 3, lo = fi & 7;
    const int gi2 = (gi & 8) | ((gi & 7) ^ (n & 7));
    u16x4 o = { f2bf(f.x), f2bf(f.y), f2bf(f.z), f2bf(f.w) };
    *(u16x4*)&Kb[((size_t)(b * 4 + he) * NN + n) * 128 + gi2 * 8 + lo] = o;
  }
}

// ---- prepass: V^T bf16 [bhe][d(128)][n(2048)], pre-swizzled within 64-n tiles ----
__global__ __launch_bounds__(256) void v_prep_kernel(const float* __restrict__ v, u16* __restrict__ Vbt) {
  __shared__ u16 Ls[64][72];
  const int t = threadIdx.x;
  const int n0 = blockIdx.x * 64;
  const int d0 = blockIdx.y * 64;
  const int z  = blockIdx.z;             // b*4+he
  #pragma unroll
  for (int p = 0; p < 4; ++p) {
    int n = p * 16 + (t >> 4), f4 = t & 15;
    float4 rv = *(const float4*)&v[((size_t)((z >> 2) * NN + n0 + n)) * DD + (z & 3) * 128 + d0 + f4 * 4];
    Ls[n][f4*4+0] = f2bf(rv.x); Ls[n][f4*4+1] = f2bf(rv.y);
    Ls[n][f4*4+2] = f2bf(rv.z); Ls[n][f4*4+3] = f2bf(rv.w);
  }
  __syncthreads();
  #pragma unroll
  for (int p = 0; p < 4; ++p) {
    int d = p * 16 + (t >> 4), c4 = t & 15;
    u16x4 o;
    #pragma unroll
    for (int j = 0; j < 4; ++j) o[j] = Ls[c4*4+j][d];
    int n2 = (((c4 >> 1) ^ (d & 7)) << 3) + (c4 & 1) * 4;
    *(u16x4*)&Vbt[((size_t)z * 128 + d0 + d) * NN + n0 + n2] = o;
  }
}

// ---- prepass: W -> bf16 linear ----
__global__ __launch_bounds__(256) void w_prep_kernel(const float* __restrict__ Wsrc, u16* __restrict__ Wb) {
  const size_t idx = (size_t)blockIdx.x * 256 + threadIdx.x;   // 65536 float4s
  float4 f = *(const float4*)&Wsrc[idx * 4];
  u16x4 o = { f2bf(f.x), f2bf(f.y), f2bf(f.z), f2bf(f.w) };
  *(u16x4*)&Wb[idx * 4] = o;
}

#define STAGE(bufi, kv0) do { \
    _Pragma("unroll") \
    for (int i_ = 0; i_ < 4; ++i_) { \
      int row_ = w*16 + i_*4 + (l >> 4); \
      gload16(kgb + (size_t)((kv0) + row_) * 128 + (l & 15) * 8, &Ks[bufi][(w*16 + i_*4) * 128]); \
    } \
    _Pragma("unroll") \
    for (int i_ = 0; i_ < 4; ++i_) { \
      int d_ = w*32 + i_*8 + (l >> 3); \
      gload16(vgb + (size_t)d_ * NN + (kv0) + (l & 7) * 8, &Vs[bufi][(w*32 + i_*8) * 64]); \
    } \
  } while (0)

#define HEADPROC(sa, m, ln, O, pb) do { \
    float mt = sa[0][0]; \
    _Pragma("unroll") for (int kvt_ = 0; kvt_ < 4; ++kvt_) \
      _Pragma("unroll") for (int r_ = 0; r_ < 4; ++r_) mt = fmaxf(mt, sa[kvt_][r_]); \
    mt = fmaxf(mt, __shfl_xor(mt, 16)); mt = fmaxf(mt, __shfl_xor(mt, 32)); \
    if (__any(mt > (m))) { \
      float mn = fmaxf((m), mt); float sc = exp2f((m) - mn); (m) = mn; (ln) *= sc; \
      _Pragma("unroll") for (int dt_ = 0; dt_ < 8; ++dt_) O[dt_] *= sc; \
    } \
    float rs = 0.f; \
    _Pragma("unroll") for (int kvt_ = 0; kvt_ < 4; ++kvt_) \
      _Pragma("unroll") for (int r_ = 0; r_ < 4; ++r_) { \
        float p_ = exp2f(sa[kvt_][r_] - (m)); sa[kvt_][r_] = p_; rs += p_; } \
    rs += __shfl_xor(rs, 16); rs += __shfl_xor(rs, 32); (ln) += rs; \
    unsigned pk_[4][2]; \
    _Pragma("unroll") for (int kvt_ = 0; kvt_ < 4; ++kvt_) { \
      asm("v_cvt_pk_bf16_f32 %0, %1, %2" : "=v"(pk_[kvt_][0]) : "v"(sa[kvt_][0]), "v"(sa[kvt_][1])); \
      asm("v_cvt_pk_bf16_f32 %0, %1, %2" : "=v"(pk_[kvt_][1]) : "v"(sa[kvt_][2]), "v"(sa[kvt_][3])); \
    } \
    _Pragma("unroll") for (int kc_ = 0; kc_ < 2; ++kc_) { \
      u32x4 wds; \
      _Pragma("unroll") for (int w2_ = 0; w2_ < 4; ++w2_) { \
        int src_ = (g & 1) * 32 + (w2_ >> 1) * 16 + c; \
        unsigned A_ = (unsigned)__shfl((int)pk_[2*kc_][w2_ & 1], src_); \
        unsigned B_ = (unsigned)__shfl((int)pk_[2*kc_+1][w2_ & 1], src_); \
        wds[w2_] = (g >> 1) ? B_ : A_; \
      } \
      union { u32x4 u; bf16x8 v; } cv_; cv_.u = wds; pb[kc_] = cv_.v; \
    } \
  } while (0)

// ---- fused diff-attention: swapped QK^T, in-register softmax, O^T PV, RMSNorm ----
__global__ __launch_bounds__(256, 2) void attn2_kernel(
    const u16* __restrict__ Qb, const u16* __restrict__ Kb, const u16* __restrict__ Vbt,
    const float* __restrict__ lq1, const float* __restrict__ lk1,
    const float* __restrict__ lq2, const float* __restrict__ lk2,
    const float* __restrict__ norm_w, u16* __restrict__ Xb)
{
  __shared__ __align__(16) u16 Ks[2][64*128];
  __shared__ __align__(16) u16 Vs[2][128*64];
  __shared__ float lam_sh;

  const int t = threadIdx.x;
  const int w = t >> 6;
  const int l = t & 63;
  const int g = l >> 4;
  const int c = l & 15;

  int bid = blockIdx.x;
  const int qt = bid & 31; const int he = (bid >> 5) & 3; const int b = bid >> 7;
  const int q0 = qt * 64;
  const int bhe = b * 4 + he;

  if (t < 64) {
    float p1 = lq1[t] * lk1[t], p2 = lq2[t] * lk2[t];
    #pragma unroll
    for (int off = 32; off; off >>= 1) { p1 += __shfl_xor(p1, off); p2 += __shfl_xor(p2, off); }
    if (t == 0) lam_sh = __expf(p1) - __expf(p2) + LAMBDA_INIT;
  }

  bf16x8 qf[4];
  {
    const u16* qp = Qb + ((size_t)(b * NN) + q0 + w * 16 + c) * DD + he * 128 + g * 8;
    #pragma unroll
    for (int dk = 0; dk < 4; ++dk) qf[dk] = *(const bf16x8*)(qp + dk * 32);
  }

  f32x4 O1[8], O2[8];
  #pragma unroll
  for (int dt = 0; dt < 8; ++dt) { O1[dt] = (f32x4){0,0,0,0}; O2[dt] = (f32x4){0,0,0,0}; }
  float m1 = -INFINITY, s_l1 = 0.f, m2 = -INFINITY, s_l2 = 0.f;

  const u16* kgb = Kb + (size_t)bhe * NN * 128;
  const u16* vgb = Vbt + (size_t)bhe * 128 * NN;

  STAGE(0, 0);
  __syncthreads();
  int cur = 0;

  for (int tile = 0; tile < 32; ++tile) {
    if (tile < 31) STAGE(cur ^ 1, (tile + 1) * 64);

    // ---- S^T = K_tile x Q^T : rows k, cols q ----
    f32x4 s1a[4], s2a[4];
    #pragma unroll
    for (int kvt = 0; kvt < 4; ++kvt) {
      const int r = kvt * 16 + c;
      const u16* krow = &Ks[cur][r * 128];
      const int sw = r & 7;
      bf16x8 k10 = *(const bf16x8*)&krow[((0 + g) ^ sw) << 3];
      bf16x8 k11 = *(const bf16x8*)&krow[((4 + g) ^ sw) << 3];
      bf16x8 k20 = *(const bf16x8*)&krow[64 + (((0 + g) ^ sw) << 3)];
      bf16x8 k21 = *(const bf16x8*)&krow[64 + (((4 + g) ^ sw) << 3)];
      f32x4 a1 = {0,0,0,0}, a2 = {0,0,0,0};
      a1 = __builtin_amdgcn_mfma_f32_16x16x32_bf16(k10, qf[0], a1, 0, 0, 0);
      a1 = __builtin_amdgcn_mfma_f32_16x16x32_bf16(k11, qf[1], a1, 0, 0, 0);
      a2 = __builtin_amdgcn_mfma_f32_16x16x32_bf16(k20, qf[2], a2, 0, 0, 0);
      a2 = __builtin_amdgcn_mfma_f32_16x16x32_bf16(k21, qf[3], a2, 0, 0, 0);
      s1a[kvt] = a1; s2a[kvt] = a2;
    }

    bf16x8 pb1[2], pb2[2];
    HEADPROC(s1a, m1, s_l1, O1, pb1);
    HEADPROC(s2a, m2, s_l2, O2, pb2);

    // ---- O^T += V^T x P : rows d, cols q ----
    #pragma unroll
    for (int kc = 0; kc < 2; ++kc) {
      #pragma unroll
      for (int dt = 0; dt < 8; ++dt) {
        bf16x8 vf = *(const bf16x8*)&Vs[cur][(dt*16 + c) * 64 + (((kc*4 + g) ^ (c & 7)) << 3)];
        O1[dt] = __builtin_amdgcn_mfma_f32_16x16x32_bf16(vf, pb1[kc], O1[dt], 0, 0, 0);
        O2[dt] = __builtin_amdgcn_mfma_f32_16x16x32_bf16(vf, pb2[kc], O2[dt], 0, 0, 0);
      }
    }
    __syncthreads();
    cur ^= 1;
  }

  // ---- epilogue: diff, RMSNorm over d, store X bf16 ----
  const float lam = lam_sh;
  const float i1 = 1.f / s_l1;
  const float i2 = lam / s_l2;
  float ss = 0.f;
  #pragma unroll
  for (int dt = 0; dt < 8; ++dt)
    #pragma unroll
    for (int rr = 0; rr < 4; ++rr) {
      float o = O1[dt][rr] * i1 - O2[dt][rr] * i2;
      O1[dt][rr] = o;
      ss += o * o;
    }
  ss += __shfl_xor(ss, 16); ss += __shfl_xor(ss, 32);
  const float rstd = rsqrtf(ss * (1.f / 128.f) + EPSV);
  const size_t xo = ((size_t)(b * NN) + q0 + w * 16 + c) * DD + he * 128;
  #pragma unroll
  for (int dt = 0; dt < 8; ++dt) {
    const float4 nw = *(const float4*)&norm_w[dt * 16 + g * 4];
    u16x4 ov;
    ov[0] = f2bf(O1[dt][0] * rstd * nw.x * 0.2f);
    ov[1] = f2bf(O1[dt][1] * rstd * nw.y * 0.2f);
    ov[2] = f2bf(O1[dt][2] * rstd * nw.z * 0.2f);
    ov[3] = f2bf(O1[dt][3] * rstd * nw.w * 0.2f);
    *(u16x4*)&Xb[xo + dt * 16 + g * 4] = ov;
  }
}

// ---- projection: bf16 MFMA, 64x64 tile, double-buffered ----
#define PLOAD(k0) do { \
    _Pragma("unroll") for (int p_ = 0; p_ < 2; ++p_) { \
      int idx_ = p_*256 + t; int r_ = idx_ >> 3, gi_ = idx_ & 7; \
      ra[p_] = *(const u16x8*)&Xb[(size_t)(row0 + r_) * DD + (k0) + gi_*8]; \
      rb[p_] = *(const u16x8*)&Wb[(size_t)(col0 + r_) * DD + (k0) + gi_*8]; } \
  } while (0)
#define PWRITE(bi) do { \
    _Pragma("unroll") for (int p_ = 0; p_ < 2; ++p_) { \
      int idx_ = p_*256 + t; int r_ = idx_ >> 3, gi_ = idx_ & 7; \
      *(u16x8*)&As[bi][r_*64 + ((gi_ ^ (r_ & 7)) << 3)] = ra[p_]; \
      *(u16x8*)&Bs[bi][r_*64 + ((gi_ ^ (r_ & 7)) << 3)] = rb[p_]; } \
  } while (0)

__global__ __launch_bounds__(256, 2) void proj_mfma_kernel(
    const u16* __restrict__ Xb, const u16* __restrict__ Wb,
    const float* __restrict__ bias, float* __restrict__ out)
{
  __shared__ __align__(16) u16 As[2][64*64];
  __shared__ __align__(16) u16 Bs[2][64*64];
  const int t = threadIdx.x;
  const int w = t >> 6, l = t & 63, g = l >> 4, c = l & 15;
  const int wm = w >> 1, wn = w & 1;
  const int row0 = blockIdx.x * 64, col0 = blockIdx.y * 64;

  u16x8 ra[2], rb[2];
  f32x4 acc[2][2];
  #pragma unroll
  for (int i = 0; i < 2; ++i)
    #pragma unroll
    for (int j = 0; j < 2; ++j) acc[i][j] = (f32x4){0,0,0,0};
  float bj[2];
  #pragma unroll
  for (int j = 0; j < 2; ++j) bj[j] = bias[col0 + wn*32 + j*16 + c];

  PLOAD(0);
  PWRITE(0);
  __syncthreads();
  for (int s = 0; s < 8; ++s) {
    const int bi = s & 1;
    if (s < 7) PLOAD((s + 1) * 64);
    #pragma unroll
    for (int kc = 0; kc < 2; ++kc) {
      bf16x8 af[2], bfv[2];
      #pragma unroll
      for (int i = 0; i < 2; ++i) {
        int rowa = wm*32 + i*16 + c;
        af[i]  = *(const bf16x8*)&As[bi][rowa*64 + (((kc*4 + g) ^ (c & 7)) << 3)];
        int rowb = wn*32 + i*16 + c;
        bfv[i] = *(const bf16x8*)&Bs[bi][rowb*64 + (((kc*4 + g) ^ (c & 7)) << 3)];
      }
      #pragma unroll
      for (int i = 0; i < 2; ++i)
        #pragma unroll
        for (int j = 0; j < 2; ++j)
          acc[i][j] = __builtin_amdgcn_mfma_f32_16x16x32_bf16(af[i], bfv[j], acc[i][j], 0, 0, 0);
    }
    if (s < 7) PWRITE((s + 1) & 1);
    __syncthreads();
  }
  #pragma unroll
  for (int i = 0; i < 2; ++i)
    #pragma unroll
    for (int j = 0; j < 2; ++j)
      #pragma unroll
      for (int rr = 0; rr < 4; ++rr)
        out[(size_t)(row0 + wm*32 + i*16 + g*4 + rr) * DD + col0 + wn*32 + j*16 + c] = acc[i][j][rr] + bj[j];
}

extern "C" void kernel_launch(void* const* d_in, const int* in_sizes, int n_in,
                              void* d_out, int out_size, void* d_ws, size_t ws_size,
                              hipStream_t stream) {
    const float* q      = (const float*)d_in[0];
    const float* k      = (const float*)d_in[1];
    const float* v      = (const float*)d_in[2];
    const float* lq1    = (const float*)d_in[3];
    const float* lk1    = (const float*)d_in[4];
    const float* lq2    = (const float*)d_in[5];
    const float* lk2    = (const float*)d_in[6];
    const float* norm_w = (const float*)d_in[7];
    const float* out_w  = (const float*)d_in[8];
    const float* out_b  = (const float*)d_in[9];
    float* out = (float*)d_out;

    u16* Qb  = (u16*)d_ws;                                   // 8 MB
    u16* Kb  = (u16*)((char*)d_ws + (8u  << 20));            // 8 MB
    u16* Vbt = (u16*)((char*)d_ws + (16u << 20));            // 8 MB
    u16* Wb  = (u16*)((char*)d_ws + (24u << 20));            // 0.5 MB
    u16* Xb  = (u16*)((char*)d_ws + (25u << 20));            // 8 MB

    qk_prep_kernel<<<BB * NN, 256, 0, stream>>>(q, k, Qb, Kb);
    v_prep_kernel<<<dim3(32, 2, 16), 256, 0, stream>>>(v, Vbt);
    w_prep_kernel<<<256, 256, 0, stream>>>(out_w, Wb);
    attn2_kernel<<<512, 256, 0, stream>>>(Qb, Kb, Vbt, lq1, lk1, lq2, lk2, norm_w, Xb);
    proj_mfma_kernel<<<dim3(128, 8), 256, 0, stream>>>(Xb, Wb, out_b, out);
}